// Round 1
// baseline (159.840 us; speedup 1.0000x reference)
//
#include <hip/hip_runtime.h>
#include <hip/hip_bf16.h>

// VQ quantizer: latents [32,64,64,64] f32 (B,D,H,W), embedding [1024,64] f32.
// out = concat( quantized [32,64,64,64] f32 , vq_loss scalar ).
//
// Positions N = 32*4096 = 131072, D = 64, K = 1024.
// argmin_k (||e_k||^2 - 2 x.e_k) via bf16 MFMA 16x16x32 (A = E tile [16 codes x 32 d],
// B = X tile [32 d x 16 positions]); loss = 1.25 * mean(best_score + ||x||^2).

#define HW 4096
#define NPOS 131072
#define OUTELEMS 8388608

typedef __attribute__((ext_vector_type(8))) short bf16x8;
typedef __attribute__((ext_vector_type(4))) float f32x4;

static __device__ __forceinline__ short f2bf(float f) {
    union { __hip_bfloat16 h; short s; } u;
    u.h = __float2bfloat16(f);
    return u.s;
}

// ws layout:
//   [0, 131072)          E bf16   (1024*64*2 B)
//   [131072, 135168)     enorm f32 (1024*4 B)
//   [135168, 659456)     idx  i32  (131072*4 B)

__global__ __launch_bounds__(256) void prep_kernel(const float* __restrict__ emb,
                                                   short* __restrict__ Ebf,
                                                   float* __restrict__ enorm,
                                                   float* __restrict__ loss) {
    int code = blockIdx.x * 4 + (threadIdx.x >> 6);
    int lane = threadIdx.x & 63;
    float v = emb[code * 64 + lane];
    Ebf[code * 64 + lane] = f2bf(v);
    float s = v * v;
#pragma unroll
    for (int off = 32; off > 0; off >>= 1) s += __shfl_xor(s, off, 64);
    if (lane == 0) enorm[code] = s;
    if (blockIdx.x == 0 && threadIdx.x == 0) *loss = 0.0f;
}

__global__ __launch_bounds__(256) void argmin_kernel(const float* __restrict__ lat,
                                                     const short* __restrict__ Ebf,
                                                     const float* __restrict__ enorm,
                                                     int* __restrict__ idx_out,
                                                     float* __restrict__ loss) {
    const int wave = threadIdx.x >> 6;
    const int lane = threadIdx.x & 63;
    const int n    = lane & 15;   // column within 16-tile (position / D-col)
    const int quad = lane >> 4;   // 0..3

    const int g0 = blockIdx.x * 256;        // first global position of block
    const int b  = g0 >> 12;                // batch (4096 positions per batch)
    const int m0 = (g0 & 4095) + wave * 64; // wave's first position within batch

    const float* latb = lat + (size_t)b * 262144; // b * 64 * 4096

    // ---- load B fragments (X tiles) + fp32 ||x||^2 partials ----
    bf16x8 bfr[4][2];
    float xnorm[4];
#pragma unroll
    for (int s = 0; s < 4; ++s) {
        const float* xp = latb + m0 + s * 16 + n;
        float xs = 0.0f;
        bf16x8 f0, f1;
#pragma unroll
        for (int j = 0; j < 8; ++j) {
            float x0 = xp[(quad * 8 + j) * HW];
            float x1 = xp[(32 + quad * 8 + j) * HW];
            xs += x0 * x0 + x1 * x1;
            f0[j] = f2bf(x0);
            f1[j] = f2bf(x1);
        }
        bfr[s][0] = f0;
        bfr[s][1] = f1;
        xnorm[s] = xs;
    }

    const bf16x8* Ev  = reinterpret_cast<const bf16x8*>(Ebf);
    const f32x4*  env = reinterpret_cast<const f32x4*>(enorm);

    float best[4] = {1e30f, 1e30f, 1e30f, 1e30f};
    int   bidx[4] = {0, 0, 0, 0};
    const f32x4 zero = {0.0f, 0.0f, 0.0f, 0.0f};

    for (int ct = 0; ct < 64; ++ct) {
        // A frags: E[ct*16 + n][quad*8 .. +7] and [32 + quad*8 .. +7]
        const int rb = (ct * 16 + n) * 8;
        bf16x8 a0 = Ev[rb + quad];
        bf16x8 a1 = Ev[rb + 4 + quad];
        f32x4 en = env[ct * 4 + quad]; // enorm for codes ct*16 + quad*4 + r

        f32x4 acc[4];
#pragma unroll
        for (int s = 0; s < 4; ++s)
            acc[s] = __builtin_amdgcn_mfma_f32_16x16x32_bf16(a0, bfr[s][0], zero, 0, 0, 0);
#pragma unroll
        for (int s = 0; s < 4; ++s)
            acc[s] = __builtin_amdgcn_mfma_f32_16x16x32_bf16(a1, bfr[s][1], acc[s], 0, 0, 0);

        const int cb = ct * 16 + quad * 4;
#pragma unroll
        for (int s = 0; s < 4; ++s) {
#pragma unroll
            for (int r = 0; r < 4; ++r) {
                float sc = fmaf(acc[s][r], -2.0f, en[r]);
                bool lt = sc < best[s];
                best[s] = lt ? sc : best[s];
                bidx[s] = lt ? (cb + r) : bidx[s];
            }
        }
    }

    // ---- cross-lane reduce over the 4 row-quads sharing each column ----
#pragma unroll
    for (int off = 16; off <= 32; off <<= 1) {
#pragma unroll
        for (int s = 0; s < 4; ++s) {
            float so = __shfl_xor(best[s], off, 64);
            int   io = __shfl_xor(bidx[s], off, 64);
            float xo = __shfl_xor(xnorm[s], off, 64);
            bool take = (so < best[s]) || (so == best[s] && io < bidx[s]);
            best[s] = take ? so : best[s];
            bidx[s] = take ? io : bidx[s];
            xnorm[s] += xo;
        }
    }

    if (quad == 0) {
#pragma unroll
        for (int s = 0; s < 4; ++s)
            idx_out[b * HW + m0 + s * 16 + n] = bidx[s];
    }

    // loss contribution: each position's (best + ||x||^2), duplicated 4x across lanes
    float contrib = 0.0f;
#pragma unroll
    for (int s = 0; s < 4; ++s) contrib += best[s] + xnorm[s];
#pragma unroll
    for (int off = 32; off > 0; off >>= 1) contrib += __shfl_xor(contrib, off, 64);
    if (lane == 0)
        atomicAdd(loss, contrib * (1.25f / (8388608.0f * 4.0f)));
}

__global__ __launch_bounds__(256) void gather_kernel(const float* __restrict__ emb,
                                                     const int* __restrict__ idxbuf,
                                                     float* __restrict__ out) {
    int g = blockIdx.x * 256 + threadIdx.x;
    int b = g >> 12;
    int m = g & 4095;
    int code = idxbuf[g];
    const f32x4* erow = reinterpret_cast<const f32x4*>(emb + (size_t)code * 64);
    f32x4 v[16];
#pragma unroll
    for (int t = 0; t < 16; ++t) v[t] = erow[t];
    float* op = out + ((size_t)b << 18) + m;
#pragma unroll
    for (int t = 0; t < 16; ++t) {
        op[(size_t)(4 * t + 0) << 12] = v[t].x;
        op[(size_t)(4 * t + 1) << 12] = v[t].y;
        op[(size_t)(4 * t + 2) << 12] = v[t].z;
        op[(size_t)(4 * t + 3) << 12] = v[t].w;
    }
}

extern "C" void kernel_launch(void* const* d_in, const int* in_sizes, int n_in,
                              void* d_out, int out_size, void* d_ws, size_t ws_size,
                              hipStream_t stream) {
    const float* latents   = (const float*)d_in[0];
    const float* embedding = (const float*)d_in[1];
    float* out  = (float*)d_out;
    float* loss = out + OUTELEMS;

    char* ws = (char*)d_ws;
    short* Ebf   = (short*)ws;
    float* enorm = (float*)(ws + 131072);
    int*   idxb  = (int*)(ws + 135168);

    prep_kernel<<<256, 256, 0, stream>>>(embedding, Ebf, enorm, loss);
    argmin_kernel<<<512, 256, 0, stream>>>(latents, Ebf, enorm, idxb, loss);
    gather_kernel<<<512, 256, 0, stream>>>(embedding, idxb, out);
}

// Round 2
// 120.060 us; speedup vs baseline: 1.3313x; 1.3313x over previous
//
#include <hip/hip_runtime.h>
#include <hip/hip_bf16.h>

// VQ: latents [32,64,64,64] f32 (B,D,H,W), embedding [1024,64] f32.
// out = concat( quantized [32,64,64,64] f32 , vq_loss scalar ).
// N = 131072 positions, D = 64, K = 1024.
//
// argmin_k ||x - e_k||^2 via bf16 MFMA 16x16x32:
//   A = -2*E tile (LDS-staged, row-rotate swizzled), B = X frags (registers),
//   C-init = 1 + ||e_k||^2  =>  acc = 1 + ||e||^2 - 2 x.e  (always > 0).
// Encoded argmin: enc = (float_bits(score) & ~1023) | code ; v_min_u32.
// loss = 1.25 * mean(dist) computed from best score + fp32 ||x||^2.

#define HW 4096
#define OUTELEMS 8388608

typedef __attribute__((ext_vector_type(8))) short bf16x8;
typedef __attribute__((ext_vector_type(4))) float f32x4;

static __device__ __forceinline__ short f2bf(float f) {
    union { __hip_bfloat16 h; short s; } u;
    u.h = __float2bfloat16(f);
    return u.s;
}

// ws layout:
//   [0, 131072)        Ebf: -2*E bf16, row-rotate-swizzled (1024 x 128 B)
//   [131072, 135168)   en1: 1 + ||e||^2 f32 (1024)
//   [135168, 397312)   embT: f32 [64][1024]
//   [397312, 921600)   idx: i32 [131072]

__global__ __launch_bounds__(256) void prep_kernel(const float* __restrict__ emb,
                                                   short* __restrict__ Ebf,
                                                   float* __restrict__ en1,
                                                   float* __restrict__ embT,
                                                   float* __restrict__ loss) {
    int code = blockIdx.x * 4 + (threadIdx.x >> 6);
    int d = threadIdx.x & 63;
    float v = emb[code * 64 + d];
    int g = d >> 3, j = d & 7;
    // row-rotate swizzle: d-group g of row `code` stored at slot (g+code)&7
    Ebf[code * 64 + ((g + code) & 7) * 8 + j] = f2bf(-2.0f * v);
    embT[d * 1024 + code] = v;
    float s = v * v;
#pragma unroll
    for (int off = 32; off > 0; off >>= 1) s += __shfl_xor(s, off, 64);
    if (d == 0) en1[code] = 1.0f + s;
    if (blockIdx.x == 0 && threadIdx.x == 0) *loss = 0.0f;
}

// 512 blocks x 512 threads. Block: 256 positions (8 waves x 32), full K=1024.
// LDS: double-buffered 32 KB codebook chunks (256 codes each).
__global__ __launch_bounds__(512, 4) void argmin_kernel(
        const float* __restrict__ lat, const short* __restrict__ Ebf,
        const float* __restrict__ en1, int* __restrict__ idx_out,
        float* __restrict__ loss) {
    __shared__ __align__(16) char sbuf[65536];
    const int tid  = threadIdx.x;
    const int wave = tid >> 6;
    const int lane = tid & 63;
    const int n    = lane & 15;
    const int quad = lane >> 4;

    const int g0 = blockIdx.x * 256;
    const int b  = g0 >> 12;
    const int m0 = (g0 & 4095) + wave * 32;
    const float* latb = lat + (size_t)b * 262144;
    const char* EbfB = (const char*)Ebf;

    // ---- issue chunk-0 staging loads (in flight across X-load phase) ----
    f32x4 stg[4];
#pragma unroll
    for (int r = 0; r < 4; ++r)
        stg[r] = *(const f32x4*)(EbfB + r * 8192 + tid * 16);

    // ---- X fragments: 32 positions/wave, fp32 ||x||^2 alongside ----
    bf16x8 bfr[2][2];
    float xnorm[2];
    {
        float xv[32];
#pragma unroll
        for (int s = 0; s < 2; ++s) {
            const float* xp = latb + m0 + s * 16 + n;
#pragma unroll
            for (int j = 0; j < 8; ++j) {
                xv[s * 16 + j]     = xp[(quad * 8 + j) * HW];
                xv[s * 16 + 8 + j] = xp[(32 + quad * 8 + j) * HW];
            }
        }
#pragma unroll
        for (int s = 0; s < 2; ++s) {
            float xs = 0.0f; bf16x8 f0, f1;
#pragma unroll
            for (int j = 0; j < 8; ++j) {
                float x0 = xv[s * 16 + j], x1 = xv[s * 16 + 8 + j];
                xs += x0 * x0 + x1 * x1;
                f0[j] = f2bf(x0); f1[j] = f2bf(x1);
            }
            bfr[s][0] = f0; bfr[s][1] = f1; xnorm[s] = xs;
        }
    }

    // write chunk 0
#pragma unroll
    for (int r = 0; r < 4; ++r)
        *(f32x4*)(sbuf + r * 8192 + tid * 16) = stg[r];
    __syncthreads();

    const f32x4* en1v = (const f32x4*)en1;
    unsigned emin[2] = {0xFFFFFFFFu, 0xFFFFFFFFu};
    const int slot0 = ((quad + n) & 7) * 16;
    const int slot1 = ((quad + 4 + n) & 7) * 16;

    for (int c = 0; c < 4; ++c) {
        const char* bufc = sbuf + (c & 1) * 32768;
        char* bufn = sbuf + ((c + 1) & 1) * 32768;
        if (c < 3) {
            const char* src = EbfB + (c + 1) * 32768;
#pragma unroll
            for (int r = 0; r < 4; ++r)
                stg[r] = *(const f32x4*)(src + r * 8192 + tid * 16);
        }
        const char* arow0 = bufc + n * 128 + slot0;
        const char* arow1 = bufc + n * 128 + slot1;
#pragma unroll 4
        for (int ctl = 0; ctl < 16; ++ctl) {
            bf16x8 a0 = *(const bf16x8*)(arow0 + ctl * 2048);
            bf16x8 a1 = *(const bf16x8*)(arow1 + ctl * 2048);
            f32x4 en4 = en1v[c * 64 + ctl * 4 + quad];
            f32x4 acc[2];
#pragma unroll
            for (int s = 0; s < 2; ++s)
                acc[s] = __builtin_amdgcn_mfma_f32_16x16x32_bf16(a0, bfr[s][0], en4, 0, 0, 0);
#pragma unroll
            for (int s = 0; s < 2; ++s)
                acc[s] = __builtin_amdgcn_mfma_f32_16x16x32_bf16(a1, bfr[s][1], acc[s], 0, 0, 0);
            const unsigned cb = c * 256 + ctl * 16 + quad * 4;
#pragma unroll
            for (int s = 0; s < 2; ++s) {
#pragma unroll
                for (int r = 0; r < 4; ++r) {
                    unsigned enc = (__float_as_uint(acc[s][r]) & 0xFFFFFC00u) | (cb + r);
                    emin[s] = enc < emin[s] ? enc : emin[s];
                }
            }
        }
        if (c < 3) {
#pragma unroll
            for (int r = 0; r < 4; ++r)
                *(f32x4*)(bufn + r * 8192 + tid * 16) = stg[r];
        }
        __syncthreads();
    }

    // ---- cross-quad reduce (min enc, sum xnorm) ----
#pragma unroll
    for (int off = 16; off <= 32; off <<= 1) {
#pragma unroll
        for (int s = 0; s < 2; ++s) {
            unsigned eo = (unsigned)__shfl_xor((int)emin[s], off, 64);
            float xo = __shfl_xor(xnorm[s], off, 64);
            emin[s] = eo < emin[s] ? eo : emin[s];
            xnorm[s] += xo;
        }
    }
    if (quad == 0) {
#pragma unroll
        for (int s = 0; s < 2; ++s)
            idx_out[b * HW + m0 + s * 16 + n] = (int)(emin[s] & 1023u);
    }
    // per-position dist = (score - 1) + ||x||^2 ; each position appears in 4 lanes
    float contrib = 0.0f;
#pragma unroll
    for (int s = 0; s < 2; ++s)
        contrib += __uint_as_float(emin[s] & 0xFFFFFC00u) - 1.0f + xnorm[s];
#pragma unroll
    for (int off = 32; off > 0; off >>= 1) contrib += __shfl_xor(contrib, off, 64);
    float* wsum = (float*)sbuf;  // chunk buffers dead after final barrier
    if (lane == 0) wsum[wave] = contrib;
    __syncthreads();
    if (tid == 0) {
        float t = 0.0f;
#pragma unroll
        for (int w = 0; w < 8; ++w) t += wsum[w];
        atomicAdd(loss, t * (1.25f / (8388608.0f * 4.0f)));
    }
}

// One thread per output element: coalesced idx loads, L1-friendly embT row
// gathers (4 KB window per block), perfectly coalesced 256 B stores.
__global__ __launch_bounds__(256) void gather_kernel(const float* __restrict__ embT,
                                                     const int* __restrict__ idxb,
                                                     float* __restrict__ out) {
    int id = blockIdx.x * 256 + threadIdx.x;
    int m  = id & 4095;
    int d  = (id >> 12) & 63;
    int bbase = (id >> 18) << 12;
    int code = idxb[bbase + m];
    out[id] = embT[(d << 10) + code];
}

extern "C" void kernel_launch(void* const* d_in, const int* in_sizes, int n_in,
                              void* d_out, int out_size, void* d_ws, size_t ws_size,
                              hipStream_t stream) {
    const float* latents   = (const float*)d_in[0];
    const float* embedding = (const float*)d_in[1];
    float* out  = (float*)d_out;
    float* loss = out + OUTELEMS;

    char* ws = (char*)d_ws;
    short* Ebf   = (short*)ws;
    float* en1   = (float*)(ws + 131072);
    float* embT  = (float*)(ws + 135168);
    int*   idxb  = (int*)(ws + 397312);

    prep_kernel<<<256, 256, 0, stream>>>(embedding, Ebf, en1, embT, loss);
    argmin_kernel<<<512, 512, 0, stream>>>(latents, Ebf, en1, idxb, loss);
    gather_kernel<<<32768, 256, 0, stream>>>(embT, idxb, out);
}

// Round 3
// 106.207 us; speedup vs baseline: 1.5050x; 1.1304x over previous
//
#include <hip/hip_runtime.h>
#include <hip/hip_bf16.h>

// VQ: latents [32,64,64,64] f32 (B,D,H,W), embedding [1024,64] f32.
// out = concat( quantized [32,64,64,64] f32 , vq_loss scalar ).
// N = 131072 positions, D = 64, K = 1024.
//
// Fused design: codebook (-2E, bf16, row-rotate swizzled) lives ENTIRELY in
// LDS (128 KB) -> barrier-free K-loop of MFMA 16x16x32 with C-init = 1+||e||^2.
// Encoded argmin: enc = (bits(score) & ~1023) | code ; v_min3_u32 trees.
// Epilogue gathers quantized values from the LDS bf16 codebook (out = -0.5 *
// bf16(-2e), ~2e-6 error) with fully coalesced f32x4 stores. One block per CU.

#define HW 4096
#define OUTELEMS 8388608

typedef __attribute__((ext_vector_type(8))) short bf16x8;
typedef __attribute__((ext_vector_type(4))) float f32x4;
typedef __attribute__((ext_vector_type(4))) int i32x4;

static __device__ __forceinline__ short f2bf(float f) {
    union { __hip_bfloat16 h; short s; } u;
    u.h = __float2bfloat16(f);
    return u.s;
}
static __device__ __forceinline__ unsigned umin2(unsigned a, unsigned b) {
    return a < b ? a : b;
}

// ws layout:
//   [0, 131072)        Ebf: -2*E bf16, row-rotate-swizzled (1024 rows x 128 B)
//   [131072, 135168)   en1: 1 + ||e||^2 f32 (1024)

__global__ __launch_bounds__(256) void prep_kernel(const float* __restrict__ emb,
                                                   short* __restrict__ Ebf,
                                                   float* __restrict__ en1,
                                                   float* __restrict__ loss) {
    int code = blockIdx.x * 4 + (threadIdx.x >> 6);
    int d = threadIdx.x & 63;
    float v = emb[code * 64 + d];
    int g = d >> 3, j = d & 7;
    // row-rotate swizzle: d-group g of row `code` stored at slot (g+code)&7
    Ebf[code * 64 + ((g + code) & 7) * 8 + j] = f2bf(-2.0f * v);
    float s = v * v;
#pragma unroll
    for (int off = 32; off > 0; off >>= 1) s += __shfl_xor(s, off, 64);
    if (d == 0) en1[code] = 1.0f + s;
    if (blockIdx.x == 0 && threadIdx.x == 0) *loss = 0.0f;
}

// 256 blocks x 1024 threads (16 waves). Block: 512 positions, full K=1024.
// Dynamic LDS: [0,131072) codebook ; [131072,135168) en1 ;
//              [135168,137216) codes i32[512] ; [137216,137280) wave loss sums.
__global__ __launch_bounds__(1024, 4) void vq_kernel(
        const float* __restrict__ lat, const short* __restrict__ Ebf,
        const float* __restrict__ en1, float* __restrict__ out,
        float* __restrict__ loss) {
    extern __shared__ __align__(16) char sbuf[];
    const int tid  = threadIdx.x;
    const int wave = tid >> 6;
    const int lane = tid & 63;
    const int n    = lane & 15;
    const int quad = lane >> 4;

    const int g0 = blockIdx.x * 512;
    const int b  = g0 >> 12;
    const int mb = g0 & 4095;
    const float* latb = lat + (size_t)b * 262144;

    // ---- stage full codebook + en1 into LDS (once) ----
    {
        const f32x4* src = (const f32x4*)Ebf;
        f32x4* dst = (f32x4*)sbuf;
#pragma unroll
        for (int r = 0; r < 8; ++r)
            dst[r * 1024 + tid] = src[r * 1024 + tid];
        if (tid < 256)
            ((f32x4*)(sbuf + 131072))[tid] = ((const f32x4*)en1)[tid];
    }

    // ---- X fragments: 32 positions/wave + fp32 ||x||^2 ----
    bf16x8 bfr[2][2];
    float xnorm[2];
#pragma unroll
    for (int s = 0; s < 2; ++s) {
        const float* xp = latb + (mb + wave * 32 + s * 16 + n);
        float xs = 0.0f; bf16x8 f0, f1;
#pragma unroll
        for (int j = 0; j < 8; ++j) {
            float x0 = xp[(quad * 8 + j) * HW];
            float x1 = xp[(32 + quad * 8 + j) * HW];
            xs += x0 * x0 + x1 * x1;
            f0[j] = f2bf(x0); f1[j] = f2bf(x1);
        }
        bfr[s][0] = f0; bfr[s][1] = f1; xnorm[s] = xs;
    }
    __syncthreads();

    // ---- barrier-free K-loop over all 1024 codes ----
    const int slot0 = ((quad + n) & 7) * 16;
    const int slot1 = ((quad + 4 + n) & 7) * 16;
    const char* arowBase = sbuf + n * 128;
    const f32x4* enl = (const f32x4*)(sbuf + 131072);
    unsigned emin[2] = {0xFFFFFFFFu, 0xFFFFFFFFu};

#pragma unroll 2
    for (int ct = 0; ct < 64; ++ct) {
        const char* rb = arowBase + ct * 2048;
        bf16x8 a0 = *(const bf16x8*)(rb + slot0);
        bf16x8 a1 = *(const bf16x8*)(rb + slot1);
        f32x4 en4 = enl[ct * 4 + quad];
        f32x4 acc0 = __builtin_amdgcn_mfma_f32_16x16x32_bf16(a0, bfr[0][0], en4, 0, 0, 0);
        f32x4 acc1 = __builtin_amdgcn_mfma_f32_16x16x32_bf16(a0, bfr[1][0], en4, 0, 0, 0);
        acc0 = __builtin_amdgcn_mfma_f32_16x16x32_bf16(a1, bfr[0][1], acc0, 0, 0, 0);
        acc1 = __builtin_amdgcn_mfma_f32_16x16x32_bf16(a1, bfr[1][1], acc1, 0, 0, 0);
        const unsigned cb = ct * 16 + quad * 4;
        unsigned e0 = (__float_as_uint(acc0[0]) & 0xFFFFFC00u) | (cb + 0);
        unsigned e1 = (__float_as_uint(acc0[1]) & 0xFFFFFC00u) | (cb + 1);
        unsigned e2 = (__float_as_uint(acc0[2]) & 0xFFFFFC00u) | (cb + 2);
        unsigned e3 = (__float_as_uint(acc0[3]) & 0xFFFFFC00u) | (cb + 3);
        emin[0] = umin2(emin[0], umin2(umin2(e0, e1), umin2(e2, e3)));
        unsigned f0 = (__float_as_uint(acc1[0]) & 0xFFFFFC00u) | (cb + 0);
        unsigned f1 = (__float_as_uint(acc1[1]) & 0xFFFFFC00u) | (cb + 1);
        unsigned f2 = (__float_as_uint(acc1[2]) & 0xFFFFFC00u) | (cb + 2);
        unsigned f3 = (__float_as_uint(acc1[3]) & 0xFFFFFC00u) | (cb + 3);
        emin[1] = umin2(emin[1], umin2(umin2(f0, f1), umin2(f2, f3)));
    }

    // ---- cross-quad reduce (min enc, sum xnorm) ----
#pragma unroll
    for (int off = 16; off <= 32; off <<= 1) {
#pragma unroll
        for (int s = 0; s < 2; ++s) {
            unsigned eo = (unsigned)__shfl_xor((int)emin[s], off, 64);
            float xo = __shfl_xor(xnorm[s], off, 64);
            emin[s] = eo < emin[s] ? eo : emin[s];
            xnorm[s] += xo;
        }
    }

    int* codes = (int*)(sbuf + 135168);
    if (quad == 0) {
        codes[wave * 32 + n]      = (int)(emin[0] & 1023u);
        codes[wave * 32 + 16 + n] = (int)(emin[1] & 1023u);
    }

    // per-position dist = (score - 1) + ||x||^2 ; each position in 4 lanes
    float contrib = 0.0f;
#pragma unroll
    for (int s = 0; s < 2; ++s)
        contrib += __uint_as_float(emin[s] & 0xFFFFFC00u) - 1.0f + xnorm[s];
#pragma unroll
    for (int off = 32; off > 0; off >>= 1) contrib += __shfl_xor(contrib, off, 64);
    float* wsum = (float*)(sbuf + 137216);
    if (lane == 0) wsum[wave] = contrib;
    __syncthreads();
    if (tid == 0) {
        float t = 0.0f;
#pragma unroll
        for (int w = 0; w < 16; ++w) t += wsum[w];
        atomicAdd(loss, t * (1.25f / (8388608.0f * 4.0f)));
    }

    // ---- fused gather epilogue: LDS codebook -> coalesced f32x4 stores ----
    float* outb = out + (size_t)b * 262144 + mb;
#pragma unroll 2
    for (int i = 0; i < 8; ++i) {
        int id = i * 1024 + tid;       // 0..8191
        int d  = id >> 7;              // 0..63 (fixed per 128 threads)
        int mq = (id & 127) * 4;       // position group of 4
        i32x4 c4 = *(const i32x4*)(codes + mq);
        int g = d >> 3, j2 = (d & 7) * 2;
        unsigned u0 = *(const unsigned short*)(sbuf + c4.x * 128 + ((g + c4.x) & 7) * 16 + j2);
        unsigned u1 = *(const unsigned short*)(sbuf + c4.y * 128 + ((g + c4.y) & 7) * 16 + j2);
        unsigned u2 = *(const unsigned short*)(sbuf + c4.z * 128 + ((g + c4.z) & 7) * 16 + j2);
        unsigned u3 = *(const unsigned short*)(sbuf + c4.w * 128 + ((g + c4.w) & 7) * 16 + j2);
        f32x4 v;
        v[0] = __uint_as_float(u0 << 16) * -0.5f;
        v[1] = __uint_as_float(u1 << 16) * -0.5f;
        v[2] = __uint_as_float(u2 << 16) * -0.5f;
        v[3] = __uint_as_float(u3 << 16) * -0.5f;
        *(f32x4*)(outb + d * HW + mq) = v;
    }
}

extern "C" void kernel_launch(void* const* d_in, const int* in_sizes, int n_in,
                              void* d_out, int out_size, void* d_ws, size_t ws_size,
                              hipStream_t stream) {
    const float* latents   = (const float*)d_in[0];
    const float* embedding = (const float*)d_in[1];
    float* out  = (float*)d_out;
    float* loss = out + OUTELEMS;

    char* ws = (char*)d_ws;
    short* Ebf = (short*)ws;
    float* en1 = (float*)(ws + 131072);

    hipFuncSetAttribute((const void*)vq_kernel,
                        hipFuncAttributeMaxDynamicSharedMemorySize, 137280);

    prep_kernel<<<256, 256, 0, stream>>>(embedding, Ebf, en1, loss);
    vq_kernel<<<256, 1024, 137280, stream>>>(latents, Ebf, en1, out, loss);
}